// Round 3
// baseline (157.345 us; speedup 1.0000x reference)
//
#include <hip/hip_runtime.h>

#define B 8
#define N 256
#define H 128
#define NF 6
#define EF 15
#define TD 4
#define FH 64
#define M (B*N)

// ---------------------------------------------------------------------------
// k_init: blocks 0..255  : x = block: deg[x] (row-sum), maskT[x][t]=adj[t][x],
//                          zero ragg slice
//         blocks 256..1279: emb0 rows (B*N*H elements)
__global__ void k_init(const int* __restrict__ adj, const float* __restrict__ nf,
                       const float* __restrict__ Wemb, const float* __restrict__ bemb,
                       float* __restrict__ deg, float* __restrict__ maskT,
                       float* __restrict__ ragg, float* __restrict__ emb) {
    int t = threadIdx.x;
    if (blockIdx.x < 256) {
        int x = blockIdx.x;
        float v = (adj[x * N + t] > 0) ? 1.f : 0.f;
        for (int o = 32; o > 0; o >>= 1) v += __shfl_down(v, o);
        __shared__ float red[4];
        if ((t & 63) == 0) red[t >> 6] = v;
        __syncthreads();
        if (t == 0) deg[x] = red[0] + red[1] + red[2] + red[3];
        // maskT[i=x][j=t] = mask[j,i] = adj[j*N+i] > 0
        maskT[x * N + t] = (adj[t * N + x] > 0) ? 1.f : 0.f;
        if (t < 24) ragg[x * 24 + t] = 0.f;
    } else {
        int idx = (blockIdx.x - 256) * 256 + t;   // < M*H
        int row = idx >> 7, h = idx & 127;
        const float* x = nf + (size_t)row * NF;
        float acc = bemb[h];
#pragma unroll
        for (int k = 0; k < NF; ++k) acc += x[k] * Wemb[k * H + h];
        emb[idx] = fmaxf(acc, 0.f);
    }
}

// ---------------------------------------------------------------------------
// k_erel: block (b, ichunk of 8), thread j.
// Streams edge once: erel planes (SoA) + ragg partials via atomics.
__global__ void k_erel(const float* __restrict__ edge, const float* __restrict__ maskT,
                       float* __restrict__ e0p, float* __restrict__ e1p,
                       float* __restrict__ e2p, float* __restrict__ ragg) {
    int blk = blockIdx.x;
    int b = blk >> 5, ic = blk & 31;
    int j = threadIdx.x;
    float r0 = 0.f, r1 = 0.f, r2 = 0.f;
#pragma unroll
    for (int ii = 0; ii < 8; ++ii) {
        int i = ic * 8 + ii;
        size_t base = ((size_t)(b * N + i)) * N + j;
        const float* e = edge + base * EF + (EF - 3);
        float e0 = e[0], e1 = e[1], e2 = e[2];
        e0p[base] = e0; e1p[base] = e1; e2p[base] = e2;
        float m = maskT[i * N + j];
        r0 += m * e0; r1 += m * e1; r2 += m * e2;
    }
    float* r = ragg + ((size_t)(b * N) + j) * 3;
    atomicAdd(r + 0, r0);
    atomicAdd(r + 1, r1);
    atomicAdd(r + 2, r2);
}

// ---------------------------------------------------------------------------
// k_layer: one kernel per GNN layer. block = (b, jtile of 8 rows), 512 thr.
//   A: agg[r][:]  = sum_i mask[j,i] * emb[b,i,:]        (assoc. trick)
//   B: msg[r][:]  = agg@We + ragg@Wr + deg*msg_b
//   C: out[r][:]  = relu(emb_row@Wu1 + msg@Wu2 + ub)
//   LAST: also hi = out@W1[:H], hj = out@W1[H:2H]  (out not stored globally)
template <bool LAST>
__global__ __launch_bounds__(512) void k_layer(
    const float* __restrict__ emb, const int* __restrict__ adj,
    const float* __restrict__ ragg, const float* __restrict__ deg,
    const float* __restrict__ mwl, const float* __restrict__ mbl,
    const float* __restrict__ uwl, const float* __restrict__ ubl,
    float* __restrict__ out, const float* __restrict__ W1,
    float* __restrict__ hi, float* __restrict__ hj) {
    __shared__ float smask[8][N];    // 8 KB
    __shared__ float sagg[8][H];     // 4 KB (reused as sout for LAST)
    __shared__ float smsg[8][H];     // 4 KB
    __shared__ float semb[8][H];     // 4 KB
    int blk = blockIdx.x;
    int b = blk >> 5, jt = blk & 31;
    int tid = threadIdx.x;
    int rg = tid >> 6, cg = tid & 63;
    int j = jt * 8 + rg;
    int c0 = cg * 2;

    // stage mask rows + emb rows (coalesced)
    {
        int col = cg * 4;
        int4 a = *(const int4*)(adj + (size_t)(jt * 8 + rg) * N + col);
        smask[rg][col + 0] = (a.x > 0) ? 1.f : 0.f;
        smask[rg][col + 1] = (a.y > 0) ? 1.f : 0.f;
        smask[rg][col + 2] = (a.z > 0) ? 1.f : 0.f;
        smask[rg][col + 3] = (a.w > 0) ? 1.f : 0.f;
        float2 e2 = *(const float2*)(emb + ((size_t)(b * N) + jt * 8 + rg) * H + c0);
        *(float2*)&semb[rg][c0] = e2;
    }
    __syncthreads();

    // Phase A: masked aggregation (4 independent chains, 8 loads in flight)
    float ax0 = 0.f, ay0 = 0.f, ax1 = 0.f, ay1 = 0.f;
    const float* eb = emb + (size_t)b * N * H + c0;
#pragma unroll 2
    for (int i = 0; i < N; i += 4) {
        float m0 = smask[rg][i], m1 = smask[rg][i + 1];
        float m2 = smask[rg][i + 2], m3 = smask[rg][i + 3];
        float2 v0 = *(const float2*)(eb + (size_t)(i + 0) * H);
        float2 v1 = *(const float2*)(eb + (size_t)(i + 1) * H);
        float2 v2 = *(const float2*)(eb + (size_t)(i + 2) * H);
        float2 v3 = *(const float2*)(eb + (size_t)(i + 3) * H);
        ax0 += m0 * v0.x + m1 * v1.x;
        ay0 += m0 * v0.y + m1 * v1.y;
        ax1 += m2 * v2.x + m3 * v3.x;
        ay1 += m2 * v2.y + m3 * v3.y;
    }
    sagg[rg][c0] = ax0 + ax1;
    sagg[rg][c0 + 1] = ay0 + ay1;
    __syncthreads();

    // Phase B: msg = agg @ We + ragg@Wr + deg*mb
    const float* ra = ragg + ((size_t)(b * N) + j) * 3;
    float ra0 = ra[0], ra1 = ra[1], ra2 = ra[2], dg = deg[j];
    float mx0 = dg * mbl[c0]     + ra0 * mwl[(size_t)(H + 0) * H + c0]
              + ra1 * mwl[(size_t)(H + 1) * H + c0]
              + ra2 * mwl[(size_t)(H + 2) * H + c0];
    float my0 = dg * mbl[c0 + 1] + ra0 * mwl[(size_t)(H + 0) * H + c0 + 1]
              + ra1 * mwl[(size_t)(H + 1) * H + c0 + 1]
              + ra2 * mwl[(size_t)(H + 2) * H + c0 + 1];
    float mx1 = 0.f, my1 = 0.f;
#pragma unroll 4
    for (int k = 0; k < H; k += 2) {
        float s0 = sagg[rg][k], s1 = sagg[rg][k + 1];
        float2 w0 = *(const float2*)(mwl + (size_t)k * H + c0);
        float2 w1 = *(const float2*)(mwl + (size_t)(k + 1) * H + c0);
        mx0 += s0 * w0.x; my0 += s0 * w0.y;
        mx1 += s1 * w1.x; my1 += s1 * w1.y;
    }
    smsg[rg][c0] = mx0 + mx1;
    smsg[rg][c0 + 1] = my0 + my1;
    __syncthreads();

    // Phase C: update GEMM (K = 256)
    float ox0 = ubl[c0], oy0 = ubl[c0 + 1], ox1 = 0.f, oy1 = 0.f;
#pragma unroll 4
    for (int k = 0; k < H; k += 2) {
        float s0 = semb[rg][k], s1 = semb[rg][k + 1];
        float2 w0 = *(const float2*)(uwl + (size_t)k * H + c0);
        float2 w1 = *(const float2*)(uwl + (size_t)(k + 1) * H + c0);
        ox0 += s0 * w0.x; oy0 += s0 * w0.y;
        ox1 += s1 * w1.x; oy1 += s1 * w1.y;
    }
#pragma unroll 4
    for (int k = 0; k < H; k += 2) {
        float s0 = smsg[rg][k], s1 = smsg[rg][k + 1];
        float2 w0 = *(const float2*)(uwl + (size_t)(H + k) * H + c0);
        float2 w1 = *(const float2*)(uwl + (size_t)(H + k + 1) * H + c0);
        ox0 += s0 * w0.x; oy0 += s0 * w0.y;
        ox1 += s1 * w1.x; oy1 += s1 * w1.y;
    }
    float ox = fmaxf(ox0 + ox1, 0.f);
    float oy = fmaxf(oy0 + oy1, 0.f);

    if (!LAST) {
        *(float2*)(out + ((size_t)(b * N) + j) * H + c0) = make_float2(ox, oy);
    } else {
        sagg[rg][c0] = ox; sagg[rg][c0 + 1] = oy;   // reuse sagg as sout
        __syncthreads();
        int f = cg;
        float h0 = 0.f, h1 = 0.f, g0 = 0.f, g1 = 0.f;
#pragma unroll 4
        for (int k = 0; k < H; k += 2) {
            float s0 = sagg[rg][k], s1 = sagg[rg][k + 1];
            h0 += s0 * W1[(size_t)k * FH + f];
            g0 += s0 * W1[(size_t)(H + k) * FH + f];
            h1 += s1 * W1[(size_t)(k + 1) * FH + f];
            g1 += s1 * W1[(size_t)(H + k + 1) * FH + f];
        }
        hi[((size_t)(b * N) + j) * FH + f] = h0 + h1;
        hj[((size_t)(b * N) + j) * FH + f] = g0 + g1;
    }
}

// ---------------------------------------------------------------------------
// k_final: tile 8(i) x 32(j) per block, 256 thr, 8 blocks/CU.
__global__ __launch_bounds__(256) void k_final(
    const float* __restrict__ hi, const float* __restrict__ hj,
    const float* __restrict__ e0p, const float* __restrict__ e1p,
    const float* __restrict__ e2p, const float* __restrict__ temporal,
    const float* __restrict__ W1, const float* __restrict__ b1,
    const float* __restrict__ W2, const float* __restrict__ b2,
    float* __restrict__ flows) {
    __shared__ float his[8][FH];
    __shared__ float hjs[32][FH + 2];   // pad: (2*tj+f)%32 -> 2-way max (free)
    __shared__ float wr0[FH], wr1[FH], wr2[FH];
    __shared__ float wt0[FH], wt1[FH], wt2[FH], wt3[FH], bb[FH], w2s[FH];
    int blk = blockIdx.x;
    int jt = blk & 7, it = (blk >> 3) & 31, b = blk >> 8;
    int tid = threadIdx.x;
#pragma unroll
    for (int u = 0; u < 2; ++u) {
        int idx = u * 256 + tid;
        his[idx >> 6][idx & 63] = hi[((size_t)(b * N) + it * 8 + (idx >> 6)) * FH + (idx & 63)];
    }
#pragma unroll
    for (int u = 0; u < 8; ++u) {
        int idx = u * 256 + tid;
        hjs[idx >> 6][idx & 63] = hj[((size_t)(b * N) + jt * 32 + (idx >> 6)) * FH + (idx & 63)];
    }
    {
        int f = tid & 63, g = tid >> 6;
        if (g == 0) { wr0[f] = W1[(2 * H + 0) * FH + f]; wt0[f] = W1[(2 * H + 3) * FH + f]; bb[f] = b1[f]; }
        if (g == 1) { wr1[f] = W1[(2 * H + 1) * FH + f]; wt1[f] = W1[(2 * H + 4) * FH + f]; w2s[f] = W2[f]; }
        if (g == 2) { wr2[f] = W1[(2 * H + 2) * FH + f]; wt2[f] = W1[(2 * H + 5) * FH + f]; }
        if (g == 3) { wt3[f] = W1[(2 * H + 6) * FH + f]; }
    }
    __syncthreads();
    int ti = tid >> 5, tj = tid & 31;
    int i = it * 8 + ti, j = jt * 32 + tj;
    size_t pij = ((size_t)(b * N) + i) * N + j;
    float e0 = e0p[pij], e1 = e1p[pij], e2 = e2p[pij];
    float4 tf = *(const float4*)(temporal + pij * TD);
    float acc = 0.f;
#pragma unroll 8
    for (int f = 0; f < FH; ++f) {
        float v = his[ti][f] + hjs[tj][f] + bb[f]
                + e0 * wr0[f] + e1 * wr1[f] + e2 * wr2[f]
                + tf.x * wt0[f] + tf.y * wt1[f] + tf.z * wt2[f] + tf.w * wt3[f];
        acc += fmaxf(v, 0.f) * w2s[f];
    }
    flows[pij] = fmaxf(acc + b2[0], 0.f);
}

// ---------------------------------------------------------------------------
extern "C" void kernel_launch(void* const* d_in, const int* in_sizes, int n_in,
                              void* d_out, int out_size, void* d_ws, size_t ws_size,
                              hipStream_t stream) {
    const float* nf       = (const float*)d_in[0];
    const float* edge     = (const float*)d_in[1];
    const float* temporal = (const float*)d_in[2];
    const int*   adj      = (const int*)d_in[3];
    const float* W_emb    = (const float*)d_in[4];
    const float* b_emb    = (const float*)d_in[5];
    const float* msg_W    = (const float*)d_in[6];
    const float* msg_b    = (const float*)d_in[7];
    const float* upd_W    = (const float*)d_in[8];
    const float* upd_b    = (const float*)d_in[9];
    const float* W1       = (const float*)d_in[10];
    const float* b1       = (const float*)d_in[11];
    const float* W2       = (const float*)d_in[12];
    const float* b2       = (const float*)d_in[13];
    float* out = (float*)d_out;

    float* ws = (float*)d_ws;
    float* deg   = ws; ws += 256;
    float* ragg  = ws; ws += B * N * 3;
    float* maskT = ws; ws += N * N;
    float* embA  = ws; ws += M * H;
    float* embB  = ws; ws += M * H;
    float* hi    = ws; ws += M * FH;
    float* hj    = ws; ws += M * FH;
    float* e0p   = ws; ws += B * N * N;
    float* e1p   = ws; ws += B * N * N;
    float* e2p   = ws; ws += B * N * N;

    k_init<<<1280, 256, 0, stream>>>(adj, nf, W_emb, b_emb, deg, maskT, ragg, embA);
    k_erel<<<256, 256, 0, stream>>>(edge, maskT, e0p, e1p, e2p, ragg);

    const float* cur = embA;
    float* nxt = embB;
    for (int l = 0; l < 3; ++l) {
        const float* mwl = msg_W + (size_t)l * (H + 3) * H;
        const float* mbl = msg_b + (size_t)l * H;
        const float* uwl = upd_W + (size_t)l * 2 * H * H;
        const float* ubl = upd_b + (size_t)l * H;
        if (l < 2) {
            k_layer<false><<<256, 512, 0, stream>>>(cur, adj, ragg, deg, mwl, mbl,
                                                    uwl, ubl, nxt, W1, hi, hj);
            const float* t = cur; cur = nxt; nxt = (float*)t;
        } else {
            k_layer<true><<<256, 512, 0, stream>>>(cur, adj, ragg, deg, mwl, mbl,
                                                   uwl, ubl, nxt, W1, hi, hj);
        }
    }

    k_final<<<2048, 256, 0, stream>>>(hi, hj, e0p, e1p, e2p, temporal,
                                      W1, b1, W2, b2, out);
}

// Round 4
// 93.894 us; speedup vs baseline: 1.6758x; 1.6758x over previous
//
#include <hip/hip_runtime.h>

#define B 8
#define N 256
#define H 128
#define NF 6
#define EF 15
#define TD 4
#define FH 64
#define M (B*N)

// ---------------------------------------------------------------------------
// k_init: blocks 0..255  : deg, maskT, zero ragg.  blocks 256..1279: emb0.
__global__ void k_init(const int* __restrict__ adj, const float* __restrict__ nf,
                       const float* __restrict__ Wemb, const float* __restrict__ bemb,
                       float* __restrict__ deg, float* __restrict__ maskT,
                       float* __restrict__ ragg, float* __restrict__ emb) {
    int t = threadIdx.x;
    if (blockIdx.x < 256) {
        int x = blockIdx.x;
        float v = (adj[x * N + t] > 0) ? 1.f : 0.f;
        for (int o = 32; o > 0; o >>= 1) v += __shfl_down(v, o);
        __shared__ float red[4];
        if ((t & 63) == 0) red[t >> 6] = v;
        __syncthreads();
        if (t == 0) deg[x] = red[0] + red[1] + red[2] + red[3];
        maskT[x * N + t] = (adj[t * N + x] > 0) ? 1.f : 0.f;
        if (t < 24) ragg[x * 24 + t] = 0.f;
    } else {
        int idx = (blockIdx.x - 256) * 256 + t;
        int row = idx >> 7, h = idx & 127;
        const float* x = nf + (size_t)row * NF;
        float acc = bemb[h];
#pragma unroll
        for (int k = 0; k < NF; ++k) acc += x[k] * Wemb[k * H + h];
        emb[idx] = fmaxf(acc, 0.f);
    }
}

// ---------------------------------------------------------------------------
// k_erel: streams edge once -> SoA erel planes + ragg atomics.
__global__ void k_erel(const float* __restrict__ edge, const float* __restrict__ maskT,
                       float* __restrict__ e0p, float* __restrict__ e1p,
                       float* __restrict__ e2p, float* __restrict__ ragg) {
    int blk = blockIdx.x;
    int b = blk >> 5, ic = blk & 31;
    int j = threadIdx.x;
    float r0 = 0.f, r1 = 0.f, r2 = 0.f;
#pragma unroll
    for (int ii = 0; ii < 8; ++ii) {
        int i = ic * 8 + ii;
        size_t base = ((size_t)(b * N + i)) * N + j;
        const float* e = edge + base * EF + (EF - 3);
        float e0 = e[0], e1 = e[1], e2 = e[2];
        e0p[base] = e0; e1p[base] = e1; e2p[base] = e2;
        float m = maskT[i * N + j];
        r0 += m * e0; r1 += m * e1; r2 += m * e2;
    }
    float* r = ragg + ((size_t)(b * N) + j) * 3;
    atomicAdd(r + 0, r0);
    atomicAdd(r + 1, r1);
    atomicAdd(r + 2, r2);
}

// ---------------------------------------------------------------------------
// k_layer: fused layer, LDS-pipelined. block=(b, jt of 8 rows), 512 thr.
// Lane layout: rg = (lane>>3) row 0..7, c8 = lane&7; cg = wave*8+c8 (64 col
// pairs -> 128 cols). A-operand reads are 8-way broadcasts (padded stride);
// weight reads are 16 consecutive floats per wave (conflict-free).
// All staging via 1-barrier double-buffered chunks (prefetch regs -> LDS).
template <bool LAST>
__global__ __launch_bounds__(512) void k_layer(
    const float* __restrict__ emb, const int* __restrict__ adj,
    const float* __restrict__ ragg, const float* __restrict__ deg,
    const float* __restrict__ mwl, const float* __restrict__ mbl,
    const float* __restrict__ uwl, const float* __restrict__ ubl,
    float* __restrict__ out, const float* __restrict__ W1,
    float* __restrict__ hi, float* __restrict__ hj)
{
    __shared__ float sbuf[2][4096];      // 2 x 16 KB staging
    __shared__ float smask[8][N + 4];    // stride 260 -> banks rg*4 apart
    __shared__ float sagg[8][H + 4];     // stride 132
    __shared__ float smsg[8][H + 4];
    __shared__ float semb[8][H + 4];

    const int tid  = threadIdx.x;
    const int wave = tid >> 6;
    const int lane = tid & 63;
    const int rg   = lane >> 3;
    const int c8   = lane & 7;
    const int cg   = wave * 8 + c8;
    const int c0   = cg * 2;

    const int blk = blockIdx.x;
    const int b   = blk >> 5;
    const int jt  = blk & 31;
    const int j   = jt * 8 + rg;

    // stage mask rows (8 x 256) + this block's emb rows (8 x 128)
    {
        int r = tid >> 6, col = (tid & 63) * 4;
        int4 a = *(const int4*)(adj + (size_t)(jt * 8 + r) * N + col);
        smask[r][col + 0] = (a.x > 0) ? 1.f : 0.f;
        smask[r][col + 1] = (a.y > 0) ? 1.f : 0.f;
        smask[r][col + 2] = (a.z > 0) ? 1.f : 0.f;
        smask[r][col + 3] = (a.w > 0) ? 1.f : 0.f;
        if (tid < 256) {
            int rr = tid >> 5, cc = (tid & 31) * 4;
            *(float4*)&semb[rr][cc] =
                *(const float4*)(emb + ((size_t)(b * N) + jt * 8 + rr) * H + cc);
        }
    }

    // ===== Phase A: agg[8][128] = mask-rows @ emb[b]  (8 chunks of 32 i) ====
    {
        const float* g = emb + (size_t)b * N * H;
        float4 q0, q1;
        q0 = *(const float4*)(g + tid * 4);
        q1 = *(const float4*)(g + 2048 + tid * 4);
        *(float4*)&sbuf[0][tid * 4] = q0;
        *(float4*)&sbuf[0][2048 + tid * 4] = q1;
        q0 = *(const float4*)(g + 4096 + tid * 4);
        q1 = *(const float4*)(g + 4096 + 2048 + tid * 4);
        __syncthreads();
        float ax = 0.f, ay = 0.f;
        for (int c = 0; c < 8; ++c) {
            if (c + 1 < 8) {
                *(float4*)&sbuf[(c + 1) & 1][tid * 4] = q0;
                *(float4*)&sbuf[(c + 1) & 1][2048 + tid * 4] = q1;
            }
            if (c + 2 < 8) {
                q0 = *(const float4*)(g + (size_t)(c + 2) * 4096 + tid * 4);
                q1 = *(const float4*)(g + (size_t)(c + 2) * 4096 + 2048 + tid * 4);
            }
            const float* sb = sbuf[c & 1];
            const float* mr = &smask[rg][c * 32];
#pragma unroll
            for (int i = 0; i < 32; ++i) {
                float m = mr[i];
                ax = fmaf(m, sb[i * 128 + c0], ax);
                ay = fmaf(m, sb[i * 128 + c0 + 1], ay);
            }
            __syncthreads();
        }
        sagg[rg][c0] = ax;
        sagg[rg][c0 + 1] = ay;
    }

    // ===== Phase B: msg = agg @ We + ragg@Wr + deg*mb  (4 chunks of 32 k) ===
    float mx, my;
    {
        const float* rr = ragg + ((size_t)(b * N) + j) * 3;
        float r0v = rr[0], r1v = rr[1], r2v = rr[2], dg = deg[j];
        const float* w0 = mwl + (size_t)(H + 0) * H;
        const float* w1 = mwl + (size_t)(H + 1) * H;
        const float* w2 = mwl + (size_t)(H + 2) * H;
        mx = dg * mbl[c0]     + r0v * w0[c0]     + r1v * w1[c0]     + r2v * w2[c0];
        my = dg * mbl[c0 + 1] + r0v * w0[c0 + 1] + r1v * w1[c0 + 1] + r2v * w2[c0 + 1];

        float4 q0, q1;
        q0 = *(const float4*)(mwl + tid * 4);
        q1 = *(const float4*)(mwl + 2048 + tid * 4);
        *(float4*)&sbuf[0][tid * 4] = q0;
        *(float4*)&sbuf[0][2048 + tid * 4] = q1;
        q0 = *(const float4*)(mwl + 4096 + tid * 4);
        q1 = *(const float4*)(mwl + 4096 + 2048 + tid * 4);
        __syncthreads();
        for (int c = 0; c < 4; ++c) {
            if (c + 1 < 4) {
                *(float4*)&sbuf[(c + 1) & 1][tid * 4] = q0;
                *(float4*)&sbuf[(c + 1) & 1][2048 + tid * 4] = q1;
            }
            if (c + 2 < 4) {
                q0 = *(const float4*)(mwl + (size_t)(c + 2) * 4096 + tid * 4);
                q1 = *(const float4*)(mwl + (size_t)(c + 2) * 4096 + 2048 + tid * 4);
            }
            const float* sb = sbuf[c & 1];
            const float* ar = &sagg[rg][c * 32];
#pragma unroll
            for (int kk = 0; kk < 32; ++kk) {
                float a = ar[kk];
                mx = fmaf(a, sb[kk * 128 + c0], mx);
                my = fmaf(a, sb[kk * 128 + c0 + 1], my);
            }
            __syncthreads();
        }
        smsg[rg][c0] = mx;
        smsg[rg][c0 + 1] = my;
    }

    // ===== Phase C: out = relu([emb_row, msg] @ updW + ub)  (8 chunks) ======
    float ox, oy;
    {
        ox = ubl[c0];
        oy = ubl[c0 + 1];
        float4 q0, q1;
        q0 = *(const float4*)(uwl + tid * 4);
        q1 = *(const float4*)(uwl + 2048 + tid * 4);
        *(float4*)&sbuf[0][tid * 4] = q0;
        *(float4*)&sbuf[0][2048 + tid * 4] = q1;
        q0 = *(const float4*)(uwl + 4096 + tid * 4);
        q1 = *(const float4*)(uwl + 4096 + 2048 + tid * 4);
        __syncthreads();
        for (int c = 0; c < 8; ++c) {
            if (c + 1 < 8) {
                *(float4*)&sbuf[(c + 1) & 1][tid * 4] = q0;
                *(float4*)&sbuf[(c + 1) & 1][2048 + tid * 4] = q1;
            }
            if (c + 2 < 8) {
                q0 = *(const float4*)(uwl + (size_t)(c + 2) * 4096 + tid * 4);
                q1 = *(const float4*)(uwl + (size_t)(c + 2) * 4096 + 2048 + tid * 4);
            }
            const float* sb = sbuf[c & 1];
            const float* ar = (c < 4) ? &semb[rg][c * 32] : &smsg[rg][(c - 4) * 32];
#pragma unroll
            for (int kk = 0; kk < 32; ++kk) {
                float a = ar[kk];
                ox = fmaf(a, sb[kk * 128 + c0], ox);
                oy = fmaf(a, sb[kk * 128 + c0 + 1], oy);
            }
            __syncthreads();
        }
        ox = fmaxf(ox, 0.f);
        oy = fmaxf(oy, 0.f);
    }

    if (!LAST) {
        *(float2*)(out + ((size_t)(b * N) + j) * H + c0) = make_float2(ox, oy);
    } else {
        // ===== Phase D: hi = out@W1[:H], hj = out@W1[H:2H]  (4 chunks) =====
        sagg[rg][c0] = ox;            // reuse sagg as sout
        sagg[rg][c0 + 1] = oy;
        const int hh = wave >> 2;                    // 0 = hi, 1 = hj
        const int f0 = ((wave & 3) * 8 + c8) * 2;    // 0..62
        float4 q0, q1;
        q0 = *(const float4*)(W1 + tid * 4);
        q1 = *(const float4*)(W1 + (size_t)H * FH + tid * 4);
        *(float4*)&sbuf[0][tid * 4] = q0;
        *(float4*)&sbuf[0][2048 + tid * 4] = q1;
        q0 = *(const float4*)(W1 + 2048 + tid * 4);
        q1 = *(const float4*)(W1 + (size_t)H * FH + 2048 + tid * 4);
        __syncthreads();
        float hx = 0.f, hy = 0.f;
        for (int c = 0; c < 4; ++c) {
            if (c + 1 < 4) {
                *(float4*)&sbuf[(c + 1) & 1][tid * 4] = q0;
                *(float4*)&sbuf[(c + 1) & 1][2048 + tid * 4] = q1;
            }
            if (c + 2 < 4) {
                q0 = *(const float4*)(W1 + (size_t)(c + 2) * 2048 + tid * 4);
                q1 = *(const float4*)(W1 + (size_t)H * FH + (size_t)(c + 2) * 2048 + tid * 4);
            }
            const float* sb = &sbuf[c & 1][hh * 2048];
            const float* ar = &sagg[rg][c * 32];
#pragma unroll
            for (int kk = 0; kk < 32; ++kk) {
                float a = ar[kk];
                hx = fmaf(a, sb[kk * 64 + f0], hx);
                hy = fmaf(a, sb[kk * 64 + f0 + 1], hy);
            }
            __syncthreads();
        }
        float* dst = hh ? hj : hi;
        *(float2*)(dst + ((size_t)(b * N) + j) * FH + f0) = make_float2(hx, hy);
    }
}

// ---------------------------------------------------------------------------
// k_final: tile 8(i) x 32(j) per block, 256 thr.
__global__ __launch_bounds__(256) void k_final(
    const float* __restrict__ hi, const float* __restrict__ hj,
    const float* __restrict__ e0p, const float* __restrict__ e1p,
    const float* __restrict__ e2p, const float* __restrict__ temporal,
    const float* __restrict__ W1, const float* __restrict__ b1,
    const float* __restrict__ W2, const float* __restrict__ b2,
    float* __restrict__ flows) {
    __shared__ float his[8][FH];
    __shared__ float hjs[32][FH + 2];
    __shared__ float wr0[FH], wr1[FH], wr2[FH];
    __shared__ float wt0[FH], wt1[FH], wt2[FH], wt3[FH], bb[FH], w2s[FH];
    int blk = blockIdx.x;
    int jt = blk & 7, it = (blk >> 3) & 31, b = blk >> 8;
    int tid = threadIdx.x;
#pragma unroll
    for (int u = 0; u < 2; ++u) {
        int idx = u * 256 + tid;
        his[idx >> 6][idx & 63] = hi[((size_t)(b * N) + it * 8 + (idx >> 6)) * FH + (idx & 63)];
    }
#pragma unroll
    for (int u = 0; u < 8; ++u) {
        int idx = u * 256 + tid;
        hjs[idx >> 6][idx & 63] = hj[((size_t)(b * N) + jt * 32 + (idx >> 6)) * FH + (idx & 63)];
    }
    {
        int f = tid & 63, g = tid >> 6;
        if (g == 0) { wr0[f] = W1[(2 * H + 0) * FH + f]; wt0[f] = W1[(2 * H + 3) * FH + f]; bb[f] = b1[f]; }
        if (g == 1) { wr1[f] = W1[(2 * H + 1) * FH + f]; wt1[f] = W1[(2 * H + 4) * FH + f]; w2s[f] = W2[f]; }
        if (g == 2) { wr2[f] = W1[(2 * H + 2) * FH + f]; wt2[f] = W1[(2 * H + 5) * FH + f]; }
        if (g == 3) { wt3[f] = W1[(2 * H + 6) * FH + f]; }
    }
    __syncthreads();
    int ti = tid >> 5, tj = tid & 31;
    int i = it * 8 + ti, j = jt * 32 + tj;
    size_t pij = ((size_t)(b * N) + i) * N + j;
    float e0 = e0p[pij], e1 = e1p[pij], e2 = e2p[pij];
    float4 tf = *(const float4*)(temporal + pij * TD);
    float acc = 0.f;
#pragma unroll 8
    for (int f = 0; f < FH; ++f) {
        float v = his[ti][f] + hjs[tj][f] + bb[f]
                + e0 * wr0[f] + e1 * wr1[f] + e2 * wr2[f]
                + tf.x * wt0[f] + tf.y * wt1[f] + tf.z * wt2[f] + tf.w * wt3[f];
        acc += fmaxf(v, 0.f) * w2s[f];
    }
    flows[pij] = fmaxf(acc + b2[0], 0.f);
}

// ---------------------------------------------------------------------------
extern "C" void kernel_launch(void* const* d_in, const int* in_sizes, int n_in,
                              void* d_out, int out_size, void* d_ws, size_t ws_size,
                              hipStream_t stream) {
    const float* nf       = (const float*)d_in[0];
    const float* edge     = (const float*)d_in[1];
    const float* temporal = (const float*)d_in[2];
    const int*   adj      = (const int*)d_in[3];
    const float* W_emb    = (const float*)d_in[4];
    const float* b_emb    = (const float*)d_in[5];
    const float* msg_W    = (const float*)d_in[6];
    const float* msg_b    = (const float*)d_in[7];
    const float* upd_W    = (const float*)d_in[8];
    const float* upd_b    = (const float*)d_in[9];
    const float* W1       = (const float*)d_in[10];
    const float* b1       = (const float*)d_in[11];
    const float* W2       = (const float*)d_in[12];
    const float* b2       = (const float*)d_in[13];
    float* out = (float*)d_out;

    float* ws = (float*)d_ws;
    float* deg   = ws; ws += 256;
    float* ragg  = ws; ws += B * N * 3;
    float* maskT = ws; ws += N * N;
    float* embA  = ws; ws += M * H;
    float* embB  = ws; ws += M * H;
    float* hi    = ws; ws += M * FH;
    float* hj    = ws; ws += M * FH;
    float* e0p   = ws; ws += B * N * N;
    float* e1p   = ws; ws += B * N * N;
    float* e2p   = ws; ws += B * N * N;

    k_init<<<1280, 256, 0, stream>>>(adj, nf, W_emb, b_emb, deg, maskT, ragg, embA);
    k_erel<<<256, 256, 0, stream>>>(edge, maskT, e0p, e1p, e2p, ragg);

    const float* cur = embA;
    float* nxt = embB;
    for (int l = 0; l < 3; ++l) {
        const float* mwl = msg_W + (size_t)l * (H + 3) * H;
        const float* mbl = msg_b + (size_t)l * H;
        const float* uwl = upd_W + (size_t)l * 2 * H * H;
        const float* ubl = upd_b + (size_t)l * H;
        if (l < 2) {
            k_layer<false><<<256, 512, 0, stream>>>(cur, adj, ragg, deg, mwl, mbl,
                                                    uwl, ubl, nxt, W1, hi, hj);
            const float* t = cur; cur = nxt; nxt = (float*)t;
        } else {
            k_layer<true><<<256, 512, 0, stream>>>(cur, adj, ragg, deg, mwl, mbl,
                                                   uwl, ubl, nxt, W1, hi, hj);
        }
    }

    k_final<<<2048, 256, 0, stream>>>(hi, hj, e0p, e1p, e2p, temporal,
                                      W1, b1, W2, b2, out);
}

// Round 5
// 77.251 us; speedup vs baseline: 2.0368x; 1.2154x over previous
//
#include <hip/hip_runtime.h>

#define B 8
#define N 256
#define H 128
#define NF 6
#define EF 15
#define TD 4
#define FH 64
#define M (B*N)

typedef unsigned short u16;
using short8  = __attribute__((ext_vector_type(8))) short;
using short4v = __attribute__((ext_vector_type(4))) short;
using f32x4   = __attribute__((ext_vector_type(4))) float;

__device__ __forceinline__ u16 f2bf(float x) {
    unsigned u = __float_as_uint(x);
    u += 0x7fffu + ((u >> 16) & 1u);
    return (u16)(u >> 16);
}
__device__ __forceinline__ float bf2f(u16 h) {
    return __uint_as_float(((unsigned)h) << 16);
}

// ---------------------------------------------------------------------------
// k_prep: build transposed bf16 hi/lo weights.
//   WeT[l][c][h]  = msg_W[l][h][c]      (3 x 128 x 128)
//   UwT[l][c][k]  = upd_W[l][k][c]      (3 x 128 x 256)
//   W1T[f][k]     = W1[k][f]            (64 x 256)
__global__ void k_prep(const float* __restrict__ msg_W, const float* __restrict__ upd_W,
                       const float* __restrict__ W1,
                       u16* __restrict__ WeTh, u16* __restrict__ WeTl,
                       u16* __restrict__ UwTh, u16* __restrict__ UwTl,
                       u16* __restrict__ W1Th, u16* __restrict__ W1Tl) {
    int idx = blockIdx.x * 256 + threadIdx.x;
    float v; u16 *dh, *dl; int d;
    if (idx < 3 * 16384) {
        int l = idx / 16384, r = idx & 16383;
        int c = r >> 7, h = r & 127;
        v = msg_W[l * ((H + 3) * H) + h * H + c];
        dh = WeTh; dl = WeTl; d = idx;
    } else if (idx < 3 * 16384 + 3 * 32768) {
        int r0 = idx - 3 * 16384;
        int l = r0 / 32768, r = r0 & 32767;
        int c = r >> 8, k = r & 255;
        v = upd_W[l * (2 * H * H) + k * H + c];
        dh = UwTh; dl = UwTl; d = r0;
    } else {
        int r0 = idx - 3 * 16384 - 3 * 32768;
        int f = r0 >> 8, k = r0 & 255;
        v = W1[k * FH + f];
        dh = W1Th; dl = W1Tl; d = r0;
    }
    u16 h = f2bf(v);
    dh[d] = h;
    dl[d] = f2bf(v - bf2f(h));
}

// ---------------------------------------------------------------------------
// k_init: blocks 0..255: deg/maskT/ragg-zero.  blocks 256..383: emb0 16-row
// tiles -> bf16 hi/lo row-major + transposed.
__global__ __launch_bounds__(512) void k_init(
    const int* __restrict__ adj, const float* __restrict__ nf,
    const float* __restrict__ Wemb, const float* __restrict__ bemb,
    float* __restrict__ deg, float* __restrict__ maskT, float* __restrict__ ragg,
    u16* __restrict__ eRh, u16* __restrict__ eRl,
    u16* __restrict__ eTh, u16* __restrict__ eTl)
{
    __shared__ float red[4];
    __shared__ __align__(16) float sout[16][132];
    int t = threadIdx.x;
    if (blockIdx.x < 256) {
        int x = blockIdx.x;
        if (t < 256) {
            float v = (adj[x * N + t] > 0) ? 1.f : 0.f;
            for (int o = 32; o > 0; o >>= 1) v += __shfl_down(v, o);
            if ((t & 63) == 0) red[t >> 6] = v;
            maskT[x * N + t] = (adj[t * N + x] > 0) ? 1.f : 0.f;
            if (t < 24) ragg[x * 24 + t] = 0.f;
        }
        __syncthreads();
        if (t == 0) deg[x] = red[0] + red[1] + red[2] + red[3];
    } else {
        int tile = blockIdx.x - 256;          // 0..127
        int row = t >> 5, h0 = (t & 31) * 4;
        int gr = tile * 16 + row;
        float xv[NF];
#pragma unroll
        for (int k = 0; k < NF; ++k) xv[k] = nf[gr * NF + k];
#pragma unroll
        for (int c = 0; c < 4; ++c) {
            float a = bemb[h0 + c];
#pragma unroll
            for (int k = 0; k < NF; ++k) a += xv[k] * Wemb[k * H + h0 + c];
            sout[row][h0 + c] = fmaxf(a, 0.f);
        }
        __syncthreads();
        {   // row-major bf16 hi/lo
            float4 v = *(const float4*)&sout[row][h0];
            short4v ph, pl;
            float xs[4] = {v.x, v.y, v.z, v.w};
#pragma unroll
            for (int c = 0; c < 4; ++c) {
                u16 h = f2bf(xs[c]);
                ph[c] = (short)h;
                pl[c] = (short)f2bf(xs[c] - bf2f(h));
            }
            *(short4v*)&eRh[(size_t)gr * H + h0] = ph;
            *(short4v*)&eRl[(size_t)gr * H + h0] = pl;
        }
        {   // transposed: eT[b][h][j]
            int hh = t >> 2, jj = (t & 3) * 4;
            short4v th, tl;
#pragma unroll
            for (int r = 0; r < 4; ++r) {
                float x = sout[jj + r][hh];
                u16 h = f2bf(x);
                th[r] = (short)h;
                tl[r] = (short)f2bf(x - bf2f(h));
            }
            size_t o = (size_t)(tile >> 4) * H * N + (size_t)hh * N + ((tile & 15) * 16) + jj;
            *(short4v*)&eTh[o] = th;
            *(short4v*)&eTl[o] = tl;
        }
    }
}

// ---------------------------------------------------------------------------
// k_erel: streams edge once -> SoA erel planes + ragg atomics.
__global__ void k_erel(const float* __restrict__ edge, const float* __restrict__ maskT,
                       float* __restrict__ e0p, float* __restrict__ e1p,
                       float* __restrict__ e2p, float* __restrict__ ragg) {
    int blk = blockIdx.x;
    int b = blk >> 5, ic = blk & 31;
    int j = threadIdx.x;
    float r0 = 0.f, r1 = 0.f, r2 = 0.f;
#pragma unroll
    for (int ii = 0; ii < 8; ++ii) {
        int i = ic * 8 + ii;
        size_t base = ((size_t)(b * N + i)) * N + j;
        const float* e = edge + base * EF + (EF - 3);
        float e0 = e[0], e1 = e[1], e2 = e[2];
        e0p[base] = e0; e1p[base] = e1; e2p[base] = e2;
        float m = maskT[i * N + j];
        r0 += m * e0; r1 += m * e1; r2 += m * e2;
    }
    float* r = ragg + ((size_t)(b * N) + j) * 3;
    atomicAdd(r + 0, r0);
    atomicAdd(r + 1, r1);
    atomicAdd(r + 2, r2);
}

// ---------------------------------------------------------------------------
// k_layer: MFMA bf16 hi/lo-split fused GNN layer.
// grid 128 = (b, 16-node tile); 512 thr = 8 waves; wave w -> cols [16w,16w+16).
template <bool LAST>
__global__ __launch_bounds__(512) void k_layer(
    const u16* __restrict__ embR_hi, const u16* __restrict__ embR_lo,
    const u16* __restrict__ embT_hi, const u16* __restrict__ embT_lo,
    const int* __restrict__ adj, const float* __restrict__ ragg,
    const float* __restrict__ deg,
    const u16* __restrict__ WeT_hi, const u16* __restrict__ WeT_lo,
    const float* __restrict__ mwl, const float* __restrict__ mbl,
    const u16* __restrict__ UwT_hi, const u16* __restrict__ UwT_lo,
    const float* __restrict__ ubl,
    u16* __restrict__ oR_hi, u16* __restrict__ oR_lo,
    u16* __restrict__ oT_hi, u16* __restrict__ oT_lo,
    const u16* __restrict__ W1T_hi, const u16* __restrict__ W1T_lo,
    float* __restrict__ hi_out, float* __restrict__ hj_out)
{
    __shared__ __align__(16) u16 sbt[2][2][128][40];     // dbuf x plane x row x k
    __shared__ __align__(16) u16 smask[16][264];
    __shared__ __align__(16) u16 semb_hi[16][136], semb_lo[16][136];
    __shared__ __align__(16) u16 sagg_hi[16][136], sagg_lo[16][136];
    __shared__ __align__(16) u16 smsg_hi[16][136], smsg_lo[16][136];
    __shared__ __align__(16) float sout[16][132];

    const int t = threadIdx.x;
    const int wave = t >> 6, lane = t & 63;
    const int lrow = lane & 15;
    const int kg8  = (lane >> 4) * 8;     // fragment k offset
    const int rb   = (lane >> 4) * 4;     // D row base (verified C/D layout)
    const int cb   = wave * 16;
    const int blk  = blockIdx.x;
    const int b    = blk >> 4, tile = blk & 15;
    const int j0   = tile * 16;
    const int gb   = b * N;

    const int sp = t >> 8, task = t & 255;
    const int sh = task >> 2, sseg = (task & 3) * 8;   // sh in [0,64)

    short8 r0, r1;

    // ---- entry staging: mask rows (exact bf16 0/1) + this tile's emb rows --
    {
        int j = t >> 5, i0 = (t & 31) * 8;
        int4 a0 = *(const int4*)(adj + (j0 + j) * N + i0);
        int4 a1 = *(const int4*)(adj + (j0 + j) * N + i0 + 4);
        short8 mrow;
        mrow[0] = (a0.x > 0) ? (short)0x3F80 : (short)0;
        mrow[1] = (a0.y > 0) ? (short)0x3F80 : (short)0;
        mrow[2] = (a0.z > 0) ? (short)0x3F80 : (short)0;
        mrow[3] = (a0.w > 0) ? (short)0x3F80 : (short)0;
        mrow[4] = (a1.x > 0) ? (short)0x3F80 : (short)0;
        mrow[5] = (a1.y > 0) ? (short)0x3F80 : (short)0;
        mrow[6] = (a1.z > 0) ? (short)0x3F80 : (short)0;
        mrow[7] = (a1.w > 0) ? (short)0x3F80 : (short)0;
        *(short8*)&smask[j][i0] = mrow;
        int h0 = (t & 31) * 4;
        *(short4v*)&semb_hi[j][h0] = *(const short4v*)&embR_hi[(size_t)(gb + j0 + j) * H + h0];
        *(short4v*)&semb_lo[j][h0] = *(const short4v*)&embR_lo[(size_t)(gb + j0 + j) * H + h0];
    }

    const u16* sA_hi = embT_hi + (size_t)b * H * N;
    const u16* sA_lo = embT_lo + (size_t)b * H * N;

    auto LD = [&](const u16* srcHi, const u16* srcLo, int rs, int ko) {
        const u16* s = sp ? srcLo : srcHi;
        r0 = *(const short8*)(s + (size_t)sh * rs + ko + sseg);
        r1 = *(const short8*)(s + (size_t)(sh + 64) * rs + ko + sseg);
    };
    auto WR = [&](int buf) {
        *(short8*)&sbt[buf][sp][sh][sseg] = r0;
        *(short8*)&sbt[buf][sp][sh + 64][sseg] = r1;
    };

    // ================= Phase A: agg = mask @ emb  (K=256) =================
    f32x4 acc = {0.f, 0.f, 0.f, 0.f};
    LD(sA_hi, sA_lo, N, 0);
    WR(0);
    __syncthreads();
    for (int c = 0; c < 8; ++c) {
        if (c < 7) LD(sA_hi, sA_lo, N, (c + 1) * 32);
        short8 am = *(const short8*)&smask[lrow][c * 32 + kg8];
        short8 bh = *(const short8*)&sbt[c & 1][0][cb + lrow][kg8];
        short8 bl = *(const short8*)&sbt[c & 1][1][cb + lrow][kg8];
        acc = __builtin_amdgcn_mfma_f32_16x16x32_bf16(am, bh, acc, 0, 0, 0);
        acc = __builtin_amdgcn_mfma_f32_16x16x32_bf16(am, bl, acc, 0, 0, 0);
        if (c < 7) WR((c + 1) & 1);
        __syncthreads();
    }
#pragma unroll
    for (int r = 0; r < 4; ++r) {
        float v = acc[r];
        u16 h = f2bf(v);
        sagg_hi[rb + r][cb + lrow] = h;
        sagg_lo[rb + r][cb + lrow] = f2bf(v - bf2f(h));
    }

    // ========== Phase B: msg = agg @ We + ragg@Wr + deg*mb  (K=128) ========
    acc = (f32x4){0.f, 0.f, 0.f, 0.f};
    LD(WeT_hi, WeT_lo, H, 0);
    WR(0);
    __syncthreads();           // covers sagg writes too
    for (int c = 0; c < 4; ++c) {
        if (c < 3) LD(WeT_hi, WeT_lo, H, (c + 1) * 32);
        short8 ah = *(const short8*)&sagg_hi[lrow][c * 32 + kg8];
        short8 al = *(const short8*)&sagg_lo[lrow][c * 32 + kg8];
        short8 bh = *(const short8*)&sbt[c & 1][0][cb + lrow][kg8];
        short8 bl = *(const short8*)&sbt[c & 1][1][cb + lrow][kg8];
        acc = __builtin_amdgcn_mfma_f32_16x16x32_bf16(ah, bh, acc, 0, 0, 0);
        acc = __builtin_amdgcn_mfma_f32_16x16x32_bf16(ah, bl, acc, 0, 0, 0);
        acc = __builtin_amdgcn_mfma_f32_16x16x32_bf16(al, bh, acc, 0, 0, 0);
        if (c < 3) WR((c + 1) & 1);
        __syncthreads();
    }
    {
        int hp = cb + lrow;
        float w0 = mwl[(H + 0) * H + hp];
        float w1 = mwl[(H + 1) * H + hp];
        float w2 = mwl[(H + 2) * H + hp];
        float mb = mbl[hp];
#pragma unroll
        for (int r = 0; r < 4; ++r) {
            int jl = j0 + rb + r;
            const float* ra = ragg + (size_t)(gb + jl) * 3;
            float v = acc[r] + deg[jl] * mb + ra[0] * w0 + ra[1] * w1 + ra[2] * w2;
            u16 h = f2bf(v);
            smsg_hi[rb + r][hp] = h;
            smsg_lo[rb + r][hp] = f2bf(v - bf2f(h));
        }
    }

    // ====== Phase C: out = relu([emb,msg] @ updW + ub)  (K=256) ============
    acc = (f32x4){0.f, 0.f, 0.f, 0.f};
    LD(UwT_hi, UwT_lo, 2 * H, 0);
    WR(0);
    __syncthreads();           // covers smsg writes too
    for (int c = 0; c < 8; ++c) {
        if (c < 7) LD(UwT_hi, UwT_lo, 2 * H, (c + 1) * 32);
        int kc = (c & 3) * 32 + kg8;
        short8 ah, al;
        if (c < 4) {
            ah = *(const short8*)&semb_hi[lrow][kc];
            al = *(const short8*)&semb_lo[lrow][kc];
        } else {
            ah = *(const short8*)&smsg_hi[lrow][kc];
            al = *(const short8*)&smsg_lo[lrow][kc];
        }
        short8 bh = *(const short8*)&sbt[c & 1][0][cb + lrow][kg8];
        short8 bl = *(const short8*)&sbt[c & 1][1][cb + lrow][kg8];
        acc = __builtin_amdgcn_mfma_f32_16x16x32_bf16(ah, bh, acc, 0, 0, 0);
        acc = __builtin_amdgcn_mfma_f32_16x16x32_bf16(ah, bl, acc, 0, 0, 0);
        acc = __builtin_amdgcn_mfma_f32_16x16x32_bf16(al, bh, acc, 0, 0, 0);
        if (c < 7) WR((c + 1) & 1);
        __syncthreads();
    }
    {
        float ub = ubl[cb + lrow];
#pragma unroll
        for (int r = 0; r < 4; ++r) {
            float v = fmaxf(acc[r] + ub, 0.f);
            if constexpr (LAST) {
                u16 h = f2bf(v);
                sagg_hi[rb + r][cb + lrow] = h;
                sagg_lo[rb + r][cb + lrow] = f2bf(v - bf2f(h));
            } else {
                sout[rb + r][cb + lrow] = v;
            }
        }
    }
    __syncthreads();

    if constexpr (!LAST) {
        {   // row-major bf16 hi/lo out
            int row = t >> 5, h0 = (t & 31) * 4;
            int gr = gb + j0 + row;
            float4 v = *(const float4*)&sout[row][h0];
            float xs[4] = {v.x, v.y, v.z, v.w};
            short4v ph, pl;
#pragma unroll
            for (int c = 0; c < 4; ++c) {
                u16 h = f2bf(xs[c]);
                ph[c] = (short)h;
                pl[c] = (short)f2bf(xs[c] - bf2f(h));
            }
            *(short4v*)&oR_hi[(size_t)gr * H + h0] = ph;
            *(short4v*)&oR_lo[(size_t)gr * H + h0] = pl;
        }
        {   // transposed out
            int hh = t >> 2, jj = (t & 3) * 4;
            short4v th, tl;
#pragma unroll
            for (int r = 0; r < 4; ++r) {
                float x = sout[jj + r][hh];
                u16 h = f2bf(x);
                th[r] = (short)h;
                tl[r] = (short)f2bf(x - bf2f(h));
            }
            size_t o = (size_t)b * H * N + (size_t)hh * N + j0 + jj;
            *(short4v*)&oT_hi[o] = th;
            *(short4v*)&oT_lo[o] = tl;
        }
    } else {
        // ===== Phase D: hi = out@W1[:H], hj = out@W1[H:2H]  (K=128) ========
        acc = (f32x4){0.f, 0.f, 0.f, 0.f};
        auto LDD = [&](int ko) {
            const u16* s = sp ? W1T_lo : W1T_hi;
            r0 = *(const short8*)(s + (size_t)sh * 256 + ko + sseg);           // Wi rows
            r1 = *(const short8*)(s + (size_t)sh * 256 + 128 + ko + sseg);     // Wj rows
        };
        LDD(0);
        WR(0);
        __syncthreads();
        const int br = ((wave >= 4) ? 64 : 0) + (wave & 3) * 16 + lrow;
        for (int c = 0; c < 4; ++c) {
            if (c < 3) LDD((c + 1) * 32);
            short8 ah = *(const short8*)&sagg_hi[lrow][c * 32 + kg8];
            short8 al = *(const short8*)&sagg_lo[lrow][c * 32 + kg8];
            short8 bh = *(const short8*)&sbt[c & 1][0][br][kg8];
            short8 bl = *(const short8*)&sbt[c & 1][1][br][kg8];
            acc = __builtin_amdgcn_mfma_f32_16x16x32_bf16(ah, bh, acc, 0, 0, 0);
            acc = __builtin_amdgcn_mfma_f32_16x16x32_bf16(ah, bl, acc, 0, 0, 0);
            acc = __builtin_amdgcn_mfma_f32_16x16x32_bf16(al, bh, acc, 0, 0, 0);
            if (c < 3) WR((c + 1) & 1);
            __syncthreads();
        }
        int colc = ((wave >= 4) ? 64 : 0) + (wave & 3) * 16 + lrow;
#pragma unroll
        for (int r = 0; r < 4; ++r) sout[rb + r][colc] = acc[r];
        __syncthreads();
        int row = t >> 5, c0 = (t & 31) * 4;
        int gr = gb + j0 + row;
        float4 v = *(const float4*)&sout[row][c0];
        if (c0 < 64) *(float4*)&hi_out[(size_t)gr * FH + c0] = v;
        else         *(float4*)&hj_out[(size_t)gr * FH + (c0 - 64)] = v;
    }
}

// ---------------------------------------------------------------------------
// k_final: tile 8(i) x 32(j) per block, 256 thr.
__global__ __launch_bounds__(256) void k_final(
    const float* __restrict__ hi, const float* __restrict__ hj,
    const float* __restrict__ e0p, const float* __restrict__ e1p,
    const float* __restrict__ e2p, const float* __restrict__ temporal,
    const float* __restrict__ W1, const float* __restrict__ b1,
    const float* __restrict__ W2, const float* __restrict__ b2,
    float* __restrict__ flows) {
    __shared__ float his[8][FH];
    __shared__ float hjs[32][FH + 2];
    __shared__ float wr0[FH], wr1[FH], wr2[FH];
    __shared__ float wt0[FH], wt1[FH], wt2[FH], wt3[FH], bb[FH], w2s[FH];
    int blk = blockIdx.x;
    int jt = blk & 7, it = (blk >> 3) & 31, b = blk >> 8;
    int tid = threadIdx.x;
#pragma unroll
    for (int u = 0; u < 2; ++u) {
        int idx = u * 256 + tid;
        his[idx >> 6][idx & 63] = hi[((size_t)(b * N) + it * 8 + (idx >> 6)) * FH + (idx & 63)];
    }
#pragma unroll
    for (int u = 0; u < 8; ++u) {
        int idx = u * 256 + tid;
        hjs[idx >> 6][idx & 63] = hj[((size_t)(b * N) + jt * 32 + (idx >> 6)) * FH + (idx & 63)];
    }
    {
        int f = tid & 63, g = tid >> 6;
        if (g == 0) { wr0[f] = W1[(2 * H + 0) * FH + f]; wt0[f] = W1[(2 * H + 3) * FH + f]; bb[f] = b1[f]; }
        if (g == 1) { wr1[f] = W1[(2 * H + 1) * FH + f]; wt1[f] = W1[(2 * H + 4) * FH + f]; w2s[f] = W2[f]; }
        if (g == 2) { wr2[f] = W1[(2 * H + 2) * FH + f]; wt2[f] = W1[(2 * H + 5) * FH + f]; }
        if (g == 3) { wt3[f] = W1[(2 * H + 6) * FH + f]; }
    }
    __syncthreads();
    int ti = tid >> 5, tj = tid & 31;
    int i = it * 8 + ti, j = jt * 32 + tj;
    size_t pij = ((size_t)(b * N) + i) * N + j;
    float e0 = e0p[pij], e1 = e1p[pij], e2 = e2p[pij];
    float4 tf = *(const float4*)(temporal + pij * TD);
    float acc = 0.f;
#pragma unroll 8
    for (int f = 0; f < FH; ++f) {
        float v = his[ti][f] + hjs[tj][f] + bb[f]
                + e0 * wr0[f] + e1 * wr1[f] + e2 * wr2[f]
                + tf.x * wt0[f] + tf.y * wt1[f] + tf.z * wt2[f] + tf.w * wt3[f];
        acc += fmaxf(v, 0.f) * w2s[f];
    }
    flows[pij] = fmaxf(acc + b2[0], 0.f);
}

// ---------------------------------------------------------------------------
extern "C" void kernel_launch(void* const* d_in, const int* in_sizes, int n_in,
                              void* d_out, int out_size, void* d_ws, size_t ws_size,
                              hipStream_t stream) {
    const float* nf       = (const float*)d_in[0];
    const float* edge     = (const float*)d_in[1];
    const float* temporal = (const float*)d_in[2];
    const int*   adj      = (const int*)d_in[3];
    const float* W_emb    = (const float*)d_in[4];
    const float* b_emb    = (const float*)d_in[5];
    const float* msg_W    = (const float*)d_in[6];
    const float* msg_b    = (const float*)d_in[7];
    const float* upd_W    = (const float*)d_in[8];
    const float* upd_b    = (const float*)d_in[9];
    const float* W1       = (const float*)d_in[10];
    const float* b1       = (const float*)d_in[11];
    const float* W2       = (const float*)d_in[12];
    const float* b2       = (const float*)d_in[13];
    float* out = (float*)d_out;
    (void)in_sizes; (void)n_in; (void)out_size; (void)ws_size;

    char* p = (char*)d_ws;
    auto take = [&](size_t bytes) { char* r = p; p += (bytes + 255) & ~(size_t)255; return r; };
    float* deg   = (float*)take(256 * 4);
    float* ragg  = (float*)take((size_t)M * 3 * 4);
    float* maskT = (float*)take((size_t)N * N * 4);
    float* e0p   = (float*)take((size_t)B * N * N * 4);
    float* e1p   = (float*)take((size_t)B * N * N * 4);
    float* e2p   = (float*)take((size_t)B * N * N * 4);
    float* hi    = (float*)take((size_t)M * FH * 4);
    float* hj    = (float*)take((size_t)M * FH * 4);
    u16* eRhA = (u16*)take((size_t)M * H * 2);
    u16* eRlA = (u16*)take((size_t)M * H * 2);
    u16* eThA = (u16*)take((size_t)M * H * 2);
    u16* eTlA = (u16*)take((size_t)M * H * 2);
    u16* eRhB = (u16*)take((size_t)M * H * 2);
    u16* eRlB = (u16*)take((size_t)M * H * 2);
    u16* eThB = (u16*)take((size_t)M * H * 2);
    u16* eTlB = (u16*)take((size_t)M * H * 2);
    u16* WeTh = (u16*)take(3 * 16384 * 2);
    u16* WeTl = (u16*)take(3 * 16384 * 2);
    u16* UwTh = (u16*)take(3 * 32768 * 2);
    u16* UwTl = (u16*)take(3 * 32768 * 2);
    u16* W1Th = (u16*)take(16384 * 2);
    u16* W1Tl = (u16*)take(16384 * 2);

    k_prep<<<640, 256, 0, stream>>>(msg_W, upd_W, W1, WeTh, WeTl, UwTh, UwTl, W1Th, W1Tl);
    k_init<<<384, 512, 0, stream>>>(adj, nf, W_emb, b_emb, deg, maskT, ragg,
                                    eRhA, eRlA, eThA, eTlA);
    k_erel<<<256, 256, 0, stream>>>(edge, maskT, e0p, e1p, e2p, ragg);

    const int mwS = (H + 3) * H;   // msg_W layer stride
    k_layer<false><<<128, 512, 0, stream>>>(
        eRhA, eRlA, eThA, eTlA, adj, ragg, deg,
        WeTh + 0 * 16384, WeTl + 0 * 16384, msg_W + 0 * mwS, msg_b + 0 * H,
        UwTh + 0 * 32768, UwTl + 0 * 32768, upd_b + 0 * H,
        eRhB, eRlB, eThB, eTlB, W1Th, W1Tl, hi, hj);
    k_layer<false><<<128, 512, 0, stream>>>(
        eRhB, eRlB, eThB, eTlB, adj, ragg, deg,
        WeTh + 1 * 16384, WeTl + 1 * 16384, msg_W + 1 * mwS, msg_b + 1 * H,
        UwTh + 1 * 32768, UwTl + 1 * 32768, upd_b + 1 * H,
        eRhA, eRlA, eThA, eTlA, W1Th, W1Tl, hi, hj);
    k_layer<true><<<128, 512, 0, stream>>>(
        eRhA, eRlA, eThA, eTlA, adj, ragg, deg,
        WeTh + 2 * 16384, WeTl + 2 * 16384, msg_W + 2 * mwS, msg_b + 2 * H,
        UwTh + 2 * 32768, UwTl + 2 * 32768, upd_b + 2 * H,
        eRhB, eRlB, eThB, eTlB, W1Th, W1Tl, hi, hj);

    k_final<<<2048, 256, 0, stream>>>(hi, hj, e0p, e1p, e2p, temporal,
                                      W1, b1, W2, b2, out);
}

// Round 6
// 73.778 us; speedup vs baseline: 2.1327x; 1.0471x over previous
//
#include <hip/hip_runtime.h>

#define B 8
#define N 256
#define H 128
#define NF 6
#define EF 15
#define TD 4
#define FH 64
#define M (B*N)

typedef unsigned short u16;
using short8  = __attribute__((ext_vector_type(8))) short;
using short4v = __attribute__((ext_vector_type(4))) short;
using f32x4   = __attribute__((ext_vector_type(4))) float;

__device__ __forceinline__ u16 f2bf(float x) {
    unsigned u = __float_as_uint(x);
    u += 0x7fffu + ((u >> 16) & 1u);
    return (u16)(u >> 16);
}
__device__ __forceinline__ float bf2f(u16 h) {
    return __uint_as_float(((unsigned)h) << 16);
}

// ---------------------------------------------------------------------------
// k_setup: one launch, role split by blockIdx.x (grid 3072, 256 thr):
//   [0,2048)    erel: block=(b,i). Stage 15KB edge row in LDS (coalesced),
//               emit SoA erel planes + per-i masked partials rp{0,1,2}.
//   [2048,2688) weight transpose -> bf16 hi/lo (WeT/UwT/W1T).
//   [2688,2816) emb0 16-row tiles -> bf16 hi/lo row-major + transposed.
//   [2816,3072) deg row-sums.
__global__ __launch_bounds__(256) void k_setup(
    const float* __restrict__ edge, const int* __restrict__ adj,
    const float* __restrict__ nf, const float* __restrict__ Wemb,
    const float* __restrict__ bemb,
    const float* __restrict__ msg_W, const float* __restrict__ upd_W,
    const float* __restrict__ W1,
    float* __restrict__ e0p, float* __restrict__ e1p, float* __restrict__ e2p,
    float* __restrict__ rp0, float* __restrict__ rp1, float* __restrict__ rp2,
    float* __restrict__ deg,
    u16* __restrict__ WeTh, u16* __restrict__ WeTl,
    u16* __restrict__ UwTh, u16* __restrict__ UwTl,
    u16* __restrict__ W1Th, u16* __restrict__ W1Tl,
    u16* __restrict__ eRh, u16* __restrict__ eRl,
    u16* __restrict__ eTh, u16* __restrict__ eTl)
{
    __shared__ __align__(16) float smem[3848];
    __shared__ float red[4];
    const int t = threadIdx.x;
    const int blk = blockIdx.x;

    if (blk < 2048) {
        // ---------------- erel role: blk = b*256 + i -----------------------
        const int i = blk & 255;
        const float* src = edge + (size_t)blk * (N * EF);
        float4* s4 = (float4*)smem;
#pragma unroll
        for (int u = 0; u < 4; ++u) {
            int idx = t + u * 256;
            if (idx < (N * EF) / 4) s4[idx] = *(const float4*)(src + idx * 4);
        }
        __syncthreads();
        const int j = t;
        float e0 = smem[j * EF + 12];
        float e1 = smem[j * EF + 13];
        float e2 = smem[j * EF + 14];
        size_t base = (size_t)blk * N + j;
        e0p[base] = e0; e1p[base] = e1; e2p[base] = e2;
        float m = (adj[j * N + i] > 0) ? 1.f : 0.f;
        rp0[base] = m * e0; rp1[base] = m * e1; rp2[base] = m * e2;
    } else if (blk < 2688) {
        // ---------------- weight transpose role -----------------------------
        int idx = (blk - 2048) * 256 + t;
        float v; u16 *dh, *dl; int d;
        if (idx < 3 * 16384) {
            int l = idx / 16384, r = idx & 16383;
            int c = r >> 7, h = r & 127;
            v = msg_W[l * ((H + 3) * H) + h * H + c];
            dh = WeTh; dl = WeTl; d = idx;
        } else if (idx < 3 * 16384 + 3 * 32768) {
            int r0 = idx - 3 * 16384;
            int l = r0 / 32768, r = r0 & 32767;
            int c = r >> 8, k = r & 255;
            v = upd_W[l * (2 * H * H) + k * H + c];
            dh = UwTh; dl = UwTl; d = r0;
        } else {
            int r0 = idx - 3 * 16384 - 3 * 32768;
            int f = r0 >> 8, k = r0 & 255;
            v = W1[k * FH + f];
            dh = W1Th; dl = W1Tl; d = r0;
        }
        u16 h = f2bf(v);
        dh[d] = h;
        dl[d] = f2bf(v - bf2f(h));
    } else if (blk < 2816) {
        // ---------------- emb0 role: 16-row tile ----------------------------
        int tile = blk - 2688;
        float (*sout)[132] = (float(*)[132])smem;
        {
            int row = t >> 4, h0 = (t & 15) * 8;
            int gr = tile * 16 + row;
            float xv[NF];
#pragma unroll
            for (int k = 0; k < NF; ++k) xv[k] = nf[gr * NF + k];
#pragma unroll
            for (int c = 0; c < 8; ++c) {
                float a = bemb[h0 + c];
#pragma unroll
                for (int k = 0; k < NF; ++k) a += xv[k] * Wemb[k * H + h0 + c];
                sout[row][h0 + c] = fmaxf(a, 0.f);
            }
        }
        __syncthreads();
        {   // row-major bf16 hi/lo (8 per thread)
            int row = t >> 4, h0 = (t & 15) * 8;
            int gr = tile * 16 + row;
            short8 ph, pl;
#pragma unroll
            for (int c = 0; c < 8; ++c) {
                float x = sout[row][h0 + c];
                u16 h = f2bf(x);
                ph[c] = (short)h;
                pl[c] = (short)f2bf(x - bf2f(h));
            }
            *(short8*)&eRh[(size_t)gr * H + h0] = ph;
            *(short8*)&eRl[(size_t)gr * H + h0] = pl;
        }
        {   // transposed: eT[b][h][j] (8 j per thread)
            int hh = t >> 1, jj = (t & 1) * 8;
            short8 th, tl;
#pragma unroll
            for (int r = 0; r < 8; ++r) {
                float x = sout[jj + r][hh];
                u16 h = f2bf(x);
                th[r] = (short)h;
                tl[r] = (short)f2bf(x - bf2f(h));
            }
            size_t o = (size_t)(tile >> 4) * H * N + (size_t)hh * N + ((tile & 15) * 16) + jj;
            *(short8*)&eTh[o] = th;
            *(short8*)&eTl[o] = tl;
        }
    } else {
        // ---------------- deg role ------------------------------------------
        int jr = blk - 2816;
        float v = (adj[jr * N + t] > 0) ? 1.f : 0.f;
        for (int o = 32; o > 0; o >>= 1) v += __shfl_down(v, o);
        if ((t & 63) == 0) red[t >> 6] = v;
        __syncthreads();
        if (t == 0) deg[jr] = red[0] + red[1] + red[2] + red[3];
    }
}

// ---------------------------------------------------------------------------
// Depth-2 staging pipeline: sbt[buf] holds chunk c (buf=c&1); regs pA/pB hold
// chunks c+1 (write next) and c+2 (in flight). One barrier per chunk; the
// ds_write's vmcnt refers to loads issued a full chunk earlier.
#define PIPE(NC, LD, COMP)                          \
    LD(0, pA0, pA1);                                \
    LD(1, pB0, pB1);                                \
    WRX(0, pA0, pA1);                               \
    __syncthreads();                                \
    _Pragma("unroll")                               \
    for (int c = 0; c < (NC); c += 2) {             \
        WRX(1, pB0, pB1);                           \
        if (c + 2 < (NC)) LD(c + 2, pA0, pA1);      \
        COMP(c, 0);                                 \
        __syncthreads();                            \
        if (c + 2 < (NC)) WRX(0, pA0, pA1);         \
        if (c + 3 < (NC)) LD(c + 3, pB0, pB1);      \
        COMP(c + 1, 1);                             \
        __syncthreads();                            \
    }

// ---------------------------------------------------------------------------
// k_layer: MFMA bf16 hi/lo-split fused GNN layer.
// grid 128 = (b, 16-node tile); 512 thr = 8 waves; wave w -> cols [16w,16w+16).
template <bool FIRST, bool LAST>
__global__ __launch_bounds__(512) void k_layer(
    const u16* __restrict__ embR_hi, const u16* __restrict__ embR_lo,
    const u16* __restrict__ embT_hi, const u16* __restrict__ embT_lo,
    const int* __restrict__ adj,
    const float* __restrict__ rp0, const float* __restrict__ rp1,
    const float* __restrict__ rp2, float* __restrict__ ragg,
    const float* __restrict__ deg,
    const u16* __restrict__ WeT_hi, const u16* __restrict__ WeT_lo,
    const float* __restrict__ mwl, const float* __restrict__ mbl,
    const u16* __restrict__ UwT_hi, const u16* __restrict__ UwT_lo,
    const float* __restrict__ ubl,
    u16* __restrict__ oR_hi, u16* __restrict__ oR_lo,
    u16* __restrict__ oT_hi, u16* __restrict__ oT_lo,
    const u16* __restrict__ W1T_hi, const u16* __restrict__ W1T_lo,
    float* __restrict__ hi_out, float* __restrict__ hj_out)
{
    __shared__ __align__(16) u16 sbt[2][2][128][40];     // dbuf x plane x row x k
    __shared__ __align__(16) u16 smask[16][264];
    __shared__ __align__(16) u16 semb_hi[16][136], semb_lo[16][136];
    __shared__ __align__(16) u16 sagg_hi[16][136], sagg_lo[16][136];
    __shared__ __align__(16) u16 smsg_hi[16][136], smsg_lo[16][136];
    __shared__ __align__(16) float sout[16][132];
    __shared__ float sragg[16][4];

    const int t = threadIdx.x;
    const int wave = t >> 6, lane = t & 63;
    const int lrow = lane & 15;
    const int kg8  = (lane >> 4) * 8;     // fragment k offset
    const int rb   = (lane >> 4) * 4;     // D row base (verified C/D layout)
    const int cb   = wave * 16;
    const int blk  = blockIdx.x;
    const int b    = blk >> 4, tile = blk & 15;
    const int j0   = tile * 16;
    const int gb   = b * N;

    const int sp = t >> 8, task = t & 255;
    const int sh = task >> 2, sseg = (task & 3) * 8;   // sh in [0,64)

    short8 pA0, pA1, pB0, pB1;

    // ---- entry staging: mask rows (exact bf16 0/1) + this tile's emb rows --
    {
        int j = t >> 5, i0 = (t & 31) * 8;
        int4 a0 = *(const int4*)(adj + (j0 + j) * N + i0);
        int4 a1 = *(const int4*)(adj + (j0 + j) * N + i0 + 4);
        short8 mrow;
        mrow[0] = (a0.x > 0) ? (short)0x3F80 : (short)0;
        mrow[1] = (a0.y > 0) ? (short)0x3F80 : (short)0;
        mrow[2] = (a0.z > 0) ? (short)0x3F80 : (short)0;
        mrow[3] = (a0.w > 0) ? (short)0x3F80 : (short)0;
        mrow[4] = (a1.x > 0) ? (short)0x3F80 : (short)0;
        mrow[5] = (a1.y > 0) ? (short)0x3F80 : (short)0;
        mrow[6] = (a1.z > 0) ? (short)0x3F80 : (short)0;
        mrow[7] = (a1.w > 0) ? (short)0x3F80 : (short)0;
        *(short8*)&smask[j][i0] = mrow;
        int h0 = (t & 31) * 4;
        *(short4v*)&semb_hi[j][h0] = *(const short4v*)&embR_hi[(size_t)(gb + j0 + j) * H + h0];
        *(short4v*)&semb_lo[j][h0] = *(const short4v*)&embR_lo[(size_t)(gb + j0 + j) * H + h0];
    }

    // ---- ragg: FIRST reduces rpart planes (and publishes); else reload -----
    if constexpr (FIRST) {
        int j16 = t >> 5, ic = t & 31;
        int gj = gb + j0 + j16;
        float s0 = 0.f, s1 = 0.f, s2 = 0.f;
#pragma unroll
        for (int k = 0; k < 8; ++k) {
            size_t o = ((size_t)(gb + ic * 8 + k)) * N + (j0 + j16);
            s0 += rp0[o]; s1 += rp1[o]; s2 += rp2[o];
        }
        for (int o = 16; o > 0; o >>= 1) {
            s0 += __shfl_down(s0, o, 32);
            s1 += __shfl_down(s1, o, 32);
            s2 += __shfl_down(s2, o, 32);
        }
        if (ic == 0) {
            sragg[j16][0] = s0; sragg[j16][1] = s1; sragg[j16][2] = s2;
            float* rg = ragg + (size_t)gj * 3;
            rg[0] = s0; rg[1] = s1; rg[2] = s2;
        }
    } else {
        if (t < 48) sragg[t / 3][t % 3] = ragg[(size_t)(gb + j0 + t / 3) * 3 + (t % 3)];
    }

    const u16* sA_hi = embT_hi + (size_t)b * H * N;
    const u16* sA_lo = embT_lo + (size_t)b * H * N;

#define WRX(buf, q0, q1)                              \
    { *(short8*)&sbt[buf][sp][sh][sseg] = q0;         \
      *(short8*)&sbt[buf][sp][sh + 64][sseg] = q1; }

#define LDA(c, q0, q1)                                                        \
    { const u16* s_ = sp ? sA_lo : sA_hi;                                     \
      q0 = *(const short8*)(s_ + (size_t)sh * N + (c) * 32 + sseg);           \
      q1 = *(const short8*)(s_ + (size_t)(sh + 64) * N + (c) * 32 + sseg); }

#define LDB(c, q0, q1)                                                        \
    { const u16* s_ = sp ? WeT_lo : WeT_hi;                                   \
      q0 = *(const short8*)(s_ + (size_t)sh * H + (c) * 32 + sseg);           \
      q1 = *(const short8*)(s_ + (size_t)(sh + 64) * H + (c) * 32 + sseg); }

#define LDC(c, q0, q1)                                                        \
    { const u16* s_ = sp ? UwT_lo : UwT_hi;                                   \
      q0 = *(const short8*)(s_ + (size_t)sh * 2 * H + (c) * 32 + sseg);       \
      q1 = *(const short8*)(s_ + (size_t)(sh + 64) * 2 * H + (c) * 32 + sseg); }

#define LDD(c, q0, q1)                                                        \
    { const u16* s_ = sp ? W1T_lo : W1T_hi;                                   \
      q0 = *(const short8*)(s_ + (size_t)sh * 256 + (c) * 32 + sseg);         \
      q1 = *(const short8*)(s_ + (size_t)sh * 256 + 128 + (c) * 32 + sseg); }

#define COMPA(c, buf)                                                           \
    { short8 am = *(const short8*)&smask[lrow][(c) * 32 + kg8];                 \
      short8 bh = *(const short8*)&sbt[buf][0][cb + lrow][kg8];                 \
      short8 bl = *(const short8*)&sbt[buf][1][cb + lrow][kg8];                 \
      acc = __builtin_amdgcn_mfma_f32_16x16x32_bf16(am, bh, acc, 0, 0, 0);      \
      acc = __builtin_amdgcn_mfma_f32_16x16x32_bf16(am, bl, acc, 0, 0, 0); }

#define COMPB(c, buf)                                                           \
    { short8 ah = *(const short8*)&sagg_hi[lrow][(c) * 32 + kg8];               \
      short8 al = *(const short8*)&sagg_lo[lrow][(c) * 32 + kg8];               \
      short8 bh = *(const short8*)&sbt[buf][0][cb + lrow][kg8];                 \
      short8 bl = *(const short8*)&sbt[buf][1][cb + lrow][kg8];                 \
      acc = __builtin_amdgcn_mfma_f32_16x16x32_bf16(ah, bh, acc, 0, 0, 0);      \
      acc = __builtin_amdgcn_mfma_f32_16x16x32_bf16(ah, bl, acc, 0, 0, 0);      \
      acc = __builtin_amdgcn_mfma_f32_16x16x32_bf16(al, bh, acc, 0, 0, 0); }

#define COMPC(c, buf)                                                           \
    { int kc = ((c) & 3) * 32 + kg8; short8 ah, al;                             \
      if ((c) < 4) { ah = *(const short8*)&semb_hi[lrow][kc];                   \
                     al = *(const short8*)&semb_lo[lrow][kc]; }                 \
      else         { ah = *(const short8*)&smsg_hi[lrow][kc];                   \
                     al = *(const short8*)&smsg_lo[lrow][kc]; }                 \
      short8 bh = *(const short8*)&sbt[buf][0][cb + lrow][kg8];                 \
      short8 bl = *(const short8*)&sbt[buf][1][cb + lrow][kg8];                 \
      acc = __builtin_amdgcn_mfma_f32_16x16x32_bf16(ah, bh, acc, 0, 0, 0);      \
      acc = __builtin_amdgcn_mfma_f32_16x16x32_bf16(ah, bl, acc, 0, 0, 0);      \
      acc = __builtin_amdgcn_mfma_f32_16x16x32_bf16(al, bh, acc, 0, 0, 0); }

#define COMPD(c, buf)                                                           \
    { short8 ah = *(const short8*)&sagg_hi[lrow][(c) * 32 + kg8];               \
      short8 al = *(const short8*)&sagg_lo[lrow][(c) * 32 + kg8];               \
      short8 bh = *(const short8*)&sbt[buf][0][br][kg8];                        \
      short8 bl = *(const short8*)&sbt[buf][1][br][kg8];                        \
      acc = __builtin_amdgcn_mfma_f32_16x16x32_bf16(ah, bh, acc, 0, 0, 0);      \
      acc = __builtin_amdgcn_mfma_f32_16x16x32_bf16(ah, bl, acc, 0, 0, 0);      \
      acc = __builtin_amdgcn_mfma_f32_16x16x32_bf16(al, bh, acc, 0, 0, 0); }

    // ================= Phase A: agg = mask @ emb  (K=256) ==================
    f32x4 acc = {0.f, 0.f, 0.f, 0.f};
    PIPE(8, LDA, COMPA)
#pragma unroll
    for (int r = 0; r < 4; ++r) {
        float v = acc[r];
        u16 h = f2bf(v);
        sagg_hi[rb + r][cb + lrow] = h;
        sagg_lo[rb + r][cb + lrow] = f2bf(v - bf2f(h));
    }

    // ========== Phase B: msg = agg @ We + ragg@Wr + deg*mb  (K=128) ========
    acc = (f32x4){0.f, 0.f, 0.f, 0.f};
    PIPE(4, LDB, COMPB)      // prologue barrier covers sagg writes
    {
        int hp = cb + lrow;
        float w0 = mwl[(H + 0) * H + hp];
        float w1 = mwl[(H + 1) * H + hp];
        float w2 = mwl[(H + 2) * H + hp];
        float mb = mbl[hp];
#pragma unroll
        for (int r = 0; r < 4; ++r) {
            int jl = j0 + rb + r;
            float v = acc[r] + deg[jl] * mb
                    + sragg[rb + r][0] * w0 + sragg[rb + r][1] * w1
                    + sragg[rb + r][2] * w2;
            u16 h = f2bf(v);
            smsg_hi[rb + r][hp] = h;
            smsg_lo[rb + r][hp] = f2bf(v - bf2f(h));
        }
    }

    // ====== Phase C: out = relu([emb,msg] @ updW + ub)  (K=256) ============
    acc = (f32x4){0.f, 0.f, 0.f, 0.f};
    PIPE(8, LDC, COMPC)      // prologue barrier covers smsg writes
    {
        float ub = ubl[cb + lrow];
#pragma unroll
        for (int r = 0; r < 4; ++r) {
            float v = fmaxf(acc[r] + ub, 0.f);
            if constexpr (LAST) {
                u16 h = f2bf(v);
                sagg_hi[rb + r][cb + lrow] = h;
                sagg_lo[rb + r][cb + lrow] = f2bf(v - bf2f(h));
            } else {
                sout[rb + r][cb + lrow] = v;
            }
        }
    }
    __syncthreads();

    if constexpr (!LAST) {
        {   // row-major bf16 hi/lo out
            int row = t >> 5, h0 = (t & 31) * 4;
            int gr = gb + j0 + row;
            float4 v = *(const float4*)&sout[row][h0];
            float xs[4] = {v.x, v.y, v.z, v.w};
            short4v ph, pl;
#pragma unroll
            for (int c = 0; c < 4; ++c) {
                u16 h = f2bf(xs[c]);
                ph[c] = (short)h;
                pl[c] = (short)f2bf(xs[c] - bf2f(h));
            }
            *(short4v*)&oR_hi[(size_t)gr * H + h0] = ph;
            *(short4v*)&oR_lo[(size_t)gr * H + h0] = pl;
        }
        {   // transposed out
            int hh = t >> 2, jj = (t & 3) * 4;
            short4v th, tl;
#pragma unroll
            for (int r = 0; r < 4; ++r) {
                float x = sout[jj + r][hh];
                u16 h = f2bf(x);
                th[r] = (short)h;
                tl[r] = (short)f2bf(x - bf2f(h));
            }
            size_t o = (size_t)b * H * N + (size_t)hh * N + j0 + jj;
            *(short4v*)&oT_hi[o] = th;
            *(short4v*)&oT_lo[o] = tl;
        }
    } else {
        // ===== Phase D: hi = out@W1[:H], hj = out@W1[H:2H]  (K=128) ========
        const int br = ((wave >= 4) ? 64 : 0) + (wave & 3) * 16 + lrow;
        acc = (f32x4){0.f, 0.f, 0.f, 0.f};
        PIPE(4, LDD, COMPD)  // prologue barrier covers sagg(out) writes
#pragma unroll
        for (int r = 0; r < 4; ++r) sout[rb + r][br] = acc[r];
        __syncthreads();
        int row = t >> 5, c0 = (t & 31) * 4;
        int gr = gb + j0 + row;
        float4 v = *(const float4*)&sout[row][c0];
        if (c0 < 64) *(float4*)&hi_out[(size_t)gr * FH + c0] = v;
        else         *(float4*)&hj_out[(size_t)gr * FH + (c0 - 64)] = v;
    }
#undef WRX
#undef LDA
#undef LDB
#undef LDC
#undef LDD
#undef COMPA
#undef COMPB
#undef COMPC
#undef COMPD
}

// ---------------------------------------------------------------------------
// k_final: tile 8(i) x 32(j) per block, 256 thr.
__global__ __launch_bounds__(256) void k_final(
    const float* __restrict__ hi, const float* __restrict__ hj,
    const float* __restrict__ e0p, const float* __restrict__ e1p,
    const float* __restrict__ e2p, const float* __restrict__ temporal,
    const float* __restrict__ W1, const float* __restrict__ b1,
    const float* __restrict__ W2, const float* __restrict__ b2,
    float* __restrict__ flows) {
    __shared__ float his[8][FH];
    __shared__ float hjs[32][FH + 2];
    __shared__ float wr0[FH], wr1[FH], wr2[FH];
    __shared__ float wt0[FH], wt1[FH], wt2[FH], wt3[FH], bb[FH], w2s[FH];
    int blk = blockIdx.x;
    int jt = blk & 7, it = (blk >> 3) & 31, b = blk >> 8;
    int tid = threadIdx.x;
#pragma unroll
    for (int u = 0; u < 2; ++u) {
        int idx = u * 256 + tid;
        his[idx >> 6][idx & 63] = hi[((size_t)(b * N) + it * 8 + (idx >> 6)) * FH + (idx & 63)];
    }
#pragma unroll
    for (int u = 0; u < 8; ++u) {
        int idx = u * 256 + tid;
        hjs[idx >> 6][idx & 63] = hj[((size_t)(b * N) + jt * 32 + (idx >> 6)) * FH + (idx & 63)];
    }
    {
        int f = tid & 63, g = tid >> 6;
        if (g == 0) { wr0[f] = W1[(2 * H + 0) * FH + f]; wt0[f] = W1[(2 * H + 3) * FH + f]; bb[f] = b1[f]; }
        if (g == 1) { wr1[f] = W1[(2 * H + 1) * FH + f]; wt1[f] = W1[(2 * H + 4) * FH + f]; w2s[f] = W2[f]; }
        if (g == 2) { wr2[f] = W1[(2 * H + 2) * FH + f]; wt2[f] = W1[(2 * H + 5) * FH + f]; }
        if (g == 3) { wt3[f] = W1[(2 * H + 6) * FH + f]; }
    }
    __syncthreads();
    int ti = tid >> 5, tj = tid & 31;
    int i = it * 8 + ti, j = jt * 32 + tj;
    size_t pij = ((size_t)(b * N) + i) * N + j;
    float e0 = e0p[pij], e1 = e1p[pij], e2 = e2p[pij];
    float4 tf = *(const float4*)(temporal + pij * TD);
    float acc = 0.f;
#pragma unroll 8
    for (int f = 0; f < FH; ++f) {
        float v = his[ti][f] + hjs[tj][f] + bb[f]
                + e0 * wr0[f] + e1 * wr1[f] + e2 * wr2[f]
                + tf.x * wt0[f] + tf.y * wt1[f] + tf.z * wt2[f] + tf.w * wt3[f];
        acc += fmaxf(v, 0.f) * w2s[f];
    }
    flows[pij] = fmaxf(acc + b2[0], 0.f);
}

// ---------------------------------------------------------------------------
extern "C" void kernel_launch(void* const* d_in, const int* in_sizes, int n_in,
                              void* d_out, int out_size, void* d_ws, size_t ws_size,
                              hipStream_t stream) {
    const float* nf       = (const float*)d_in[0];
    const float* edge     = (const float*)d_in[1];
    const float* temporal = (const float*)d_in[2];
    const int*   adj      = (const int*)d_in[3];
    const float* W_emb    = (const float*)d_in[4];
    const float* b_emb    = (const float*)d_in[5];
    const float* msg_W    = (const float*)d_in[6];
    const float* msg_b    = (const float*)d_in[7];
    const float* upd_W    = (const float*)d_in[8];
    const float* upd_b    = (const float*)d_in[9];
    const float* W1       = (const float*)d_in[10];
    const float* b1       = (const float*)d_in[11];
    const float* W2       = (const float*)d_in[12];
    const float* b2       = (const float*)d_in[13];
    float* out = (float*)d_out;
    (void)in_sizes; (void)n_in; (void)out_size; (void)ws_size;

    char* p = (char*)d_ws;
    auto take = [&](size_t bytes) { char* r = p; p += (bytes + 255) & ~(size_t)255; return r; };
    float* deg   = (float*)take(256 * 4);
    float* ragg  = (float*)take((size_t)M * 3 * 4);
    float* e0p   = (float*)take((size_t)B * N * N * 4);
    float* e1p   = (float*)take((size_t)B * N * N * 4);
    float* e2p   = (float*)take((size_t)B * N * N * 4);
    float* rp0   = (float*)take((size_t)B * N * N * 4);
    float* rp1   = (float*)take((size_t)B * N * N * 4);
    float* rp2   = (float*)take((size_t)B * N * N * 4);
    float* hi    = (float*)take((size_t)M * FH * 4);
    float* hj    = (float*)take((size_t)M * FH * 4);
    u16* eRhA = (u16*)take((size_t)M * H * 2);
    u16* eRlA = (u16*)take((size_t)M * H * 2);
    u16* eThA = (u16*)take((size_t)M * H * 2);
    u16* eTlA = (u16*)take((size_t)M * H * 2);
    u16* eRhB = (u16*)take((size_t)M * H * 2);
    u16* eRlB = (u16*)take((size_t)M * H * 2);
    u16* eThB = (u16*)take((size_t)M * H * 2);
    u16* eTlB = (u16*)take((size_t)M * H * 2);
    u16* WeTh = (u16*)take(3 * 16384 * 2);
    u16* WeTl = (u16*)take(3 * 16384 * 2);
    u16* UwTh = (u16*)take(3 * 32768 * 2);
    u16* UwTl = (u16*)take(3 * 32768 * 2);
    u16* W1Th = (u16*)take(16384 * 2);
    u16* W1Tl = (u16*)take(16384 * 2);

    k_setup<<<3072, 256, 0, stream>>>(edge, adj, nf, W_emb, b_emb,
                                      msg_W, upd_W, W1,
                                      e0p, e1p, e2p, rp0, rp1, rp2, deg,
                                      WeTh, WeTl, UwTh, UwTl, W1Th, W1Tl,
                                      eRhA, eRlA, eThA, eTlA);

    const int mwS = (H + 3) * H;   // msg_W layer stride
    k_layer<true, false><<<128, 512, 0, stream>>>(
        eRhA, eRlA, eThA, eTlA, adj, rp0, rp1, rp2, ragg, deg,
        WeTh + 0 * 16384, WeTl + 0 * 16384, msg_W + 0 * mwS, msg_b + 0 * H,
        UwTh + 0 * 32768, UwTl + 0 * 32768, upd_b + 0 * H,
        eRhB, eRlB, eThB, eTlB, W1Th, W1Tl, hi, hj);
    k_layer<false, false><<<128, 512, 0, stream>>>(
        eRhB, eRlB, eThB, eTlB, adj, rp0, rp1, rp2, ragg, deg,
        WeTh + 1 * 16384, WeTl + 1 * 16384, msg_W + 1 * mwS, msg_b + 1 * H,
        UwTh + 1 * 32768, UwTl + 1 * 32768, upd_b + 1 * H,
        eRhA, eRlA, eThA, eTlA, W1Th, W1Tl, hi, hj);
    k_layer<false, true><<<128, 512, 0, stream>>>(
        eRhA, eRlA, eThA, eTlA, adj, rp0, rp1, rp2, ragg, deg,
        WeTh + 2 * 16384, WeTl + 2 * 16384, msg_W + 2 * mwS, msg_b + 2 * H,
        UwTh + 2 * 32768, UwTl + 2 * 32768, upd_b + 2 * H,
        eRhB, eRlB, eThB, eTlB, W1Th, W1Tl, hi, hj);

    k_final<<<2048, 256, 0, stream>>>(hi, hj, e0p, e1p, e2p, temporal,
                                      W1, b1, W2, b2, out);
}